// Round 7
// baseline (87668.896 us; speedup 1.0000x reference)
//
#include <hip/hip_runtime.h>

#define T_STEPS 1024
#define BSZ 256
#define HD 256
#define OUTC 64

// ---------------- ws layout (float offsets) ----------------
static const size_t OFF_SUM  = 0;       // [256][256] f32  (Sum_t outs, t-sequential)
static const size_t OFF_FLAG = 65536;   // int flag (x is int64?)

// x-dtype detector: if x is int64, all sampled high 32-bit words are zero.
__global__ void detect_x(const int* __restrict__ x, float* __restrict__ ws) {
    __shared__ int nonzero;
    if (threadIdx.x == 0) nonzero = 0;
    __syncthreads();
    if (x[2 * threadIdx.x + 1] != 0) nonzero = 1;   // benign same-value race
    __syncthreads();
    if (threadIdx.x == 0) *(int*)(ws + OFF_FLAG) = (nonzero == 0) ? 1 : 0;
}

// Bit-faithful f32 scan. Each block owns 4 batch rows for all 1024 steps.
// Every output element is a single f32 FMA chain, k ascending (matches BLAS
// sgemm microkernel: C element kept in one register, vfmadd over k in order).
// h_t, o_t stored f32 (LDS); Sum_t outs accumulated f32 in t order (matches
// np.mean axis-0 sequential reduction); biases added as single f32 adds.
__global__ __launch_bounds__(512) void scan_all(
    const int* __restrict__ x, const float* __restrict__ emb,
    const float* __restrict__ Wi2h, const float* __restrict__ bih,
    const float* __restrict__ Wi2o, const float* __restrict__ bio,
    const float* __restrict__ Wo2o, const float* __restrict__ boo,
    float* __restrict__ ws) {
    const int tid = threadIdx.x;
    const int j = tid & 255;          // output index (h/o/out column)
    const int s = tid >> 8;           // slot 0..1 -> handles bl = 2s, 2s+1
    const int bl0 = s * 2, bl1 = s * 2 + 1;
    const int b0 = blockIdx.x * 4;
    const int mode64 = *(const int*)(ws + OFF_FLAG);

    __shared__ float eL[4][256];
    __shared__ float hPing[4][256];
    __shared__ float hPong[4][256];
    __shared__ float oL[4][256];
    __shared__ float sumL[4][256];
    __shared__ int tokL[4];

    hPing[bl0][j] = 0.f; hPing[bl1][j] = 0.f;   // h_0 = 0
    sumL[bl0][j] = 0.f;  sumL[bl1][j] = 0.f;
    __syncthreads();

    const float4* __restrict__ Wh4  = (const float4*)(Wi2h + (size_t)j * 512);
    const float4* __restrict__ Wio4 = (const float4*)(Wi2o + (size_t)j * 512);
    const float4* __restrict__ Woo4 = (const float4*)(Wo2o + (size_t)j * 512);
    const float bih_j = bih[j], bio_j = bio[j], boo_j = boo[j];

    for (int t = 0; t < T_STEPS; ++t) {
        if (tid < 4) {
            const int idx = t * BSZ + b0 + tid;
            tokL[tid] = mode64 ? x[2 * idx] : x[idx];
        }
        __syncthreads();
        eL[bl0][j] = emb[(size_t)tokL[bl0] * HD + j];
        eL[bl1][j] = emb[(size_t)tokL[bl1] * HD + j];
        __syncthreads();

        const float (*hO)[256] = (t & 1) ? hPong : hPing;
        float (*hN)[256]       = (t & 1) ? hPing : hPong;

        // h_new[j], o[j]: FMA chain over k = 0..511 (e part then h part)
        float ah0 = 0.f, ah1 = 0.f, ao0 = 0.f, ao1 = 0.f;
        #pragma unroll 4
        for (int q = 0; q < 64; ++q) {              // k = 0..255 : e part
            const float4 wh = Wh4[q];
            const float4 wo = Wio4[q];
            const float* whp = (const float*)&wh;
            const float* wop = (const float*)&wo;
            #pragma unroll
            for (int c = 0; c < 4; ++c) {
                const float e0 = eL[bl0][q * 4 + c];
                const float e1 = eL[bl1][q * 4 + c];
                ah0 = fmaf(e0, whp[c], ah0); ah1 = fmaf(e1, whp[c], ah1);
                ao0 = fmaf(e0, wop[c], ao0); ao1 = fmaf(e1, wop[c], ao1);
            }
        }
        #pragma unroll 4
        for (int q = 64; q < 128; ++q) {            // k = 256..511 : h part
            const float4 wh = Wh4[q];
            const float4 wo = Wio4[q];
            const float* whp = (const float*)&wh;
            const float* wop = (const float*)&wo;
            #pragma unroll
            for (int c = 0; c < 4; ++c) {
                const float h0 = hO[bl0][(q - 64) * 4 + c];
                const float h1 = hO[bl1][(q - 64) * 4 + c];
                ah0 = fmaf(h0, whp[c], ah0); ah1 = fmaf(h1, whp[c], ah1);
                ao0 = fmaf(h0, wop[c], ao0); ao1 = fmaf(h1, wop[c], ao1);
            }
        }
        const float hn0 = ah0 + bih_j, hn1 = ah1 + bih_j;  // + b_i2h (f32 add)
        const float on0 = ao0 + bio_j, on1 = ao1 + bio_j;  // + b_i2o
        hN[bl0][j] = hn0; hN[bl1][j] = hn1;
        oL[bl0][j] = on0; oL[bl1][j] = on1;
        __syncthreads();

        // out[j]: FMA chain over k = 0..511 (h_new part then o part)
        float ac0 = 0.f, ac1 = 0.f;
        #pragma unroll 4
        for (int q = 0; q < 64; ++q) {              // h_new part
            const float4 w = Woo4[q];
            const float* wp = (const float*)&w;
            #pragma unroll
            for (int c = 0; c < 4; ++c) {
                ac0 = fmaf(hN[bl0][q * 4 + c], wp[c], ac0);
                ac1 = fmaf(hN[bl1][q * 4 + c], wp[c], ac1);
            }
        }
        #pragma unroll 4
        for (int q = 64; q < 128; ++q) {            // o part
            const float4 w = Woo4[q];
            const float* wp = (const float*)&w;
            #pragma unroll
            for (int c = 0; c < 4; ++c) {
                ac0 = fmaf(oL[bl0][(q - 64) * 4 + c], wp[c], ac0);
                ac1 = fmaf(oL[bl1][(q - 64) * 4 + c], wp[c], ac1);
            }
        }
        // Sum_t accumulation, t-ascending, f32 (matches np.mean axis-0 order)
        sumL[bl0][j] += (ac0 + boo_j);
        sumL[bl1][j] += (ac1 + boo_j);
        __syncthreads();
    }

    ws[OFF_SUM + (size_t)(b0 + bl0) * 256 + j] = sumL[bl0][j];
    ws[OFF_SUM + (size_t)(b0 + bl1) * 256 + j] = sumL[bl1][j];
}

// encoded = Sum/1024 (exact); logits = seq-k FMA + b_pred; log_softmax with
// f64-CR exp/log (log_s ulp deviations shift all quantized lp by whole quanta
// -> argmax invariant); first-index argmax over f32 lp.
__global__ __launch_bounds__(64) void final_k(
    const float* __restrict__ Wpred, const float* __restrict__ bpred,
    const float* __restrict__ ws, float* __restrict__ out) {
    const int b = blockIdx.x, o = threadIdx.x;
    __shared__ float enc[256];
    __shared__ float exs[64];
    __shared__ float s32s;

    #pragma unroll
    for (int u = 0; u < 4; ++u)
        enc[o * 4 + u] = ws[OFF_SUM + (size_t)b * 256 + o * 4 + u] * (1.0f / 1024.0f);
    __syncthreads();

    float acc = 0.f;
    for (int e = 0; e < 256; ++e)
        acc = fmaf(enc[e], Wpred[(size_t)o * 256 + e], acc);
    acc += bpred[o];                      // logits[b][o], f32

    // row max (exact)
    float m = acc;
    #pragma unroll
    for (int d = 1; d < 64; d <<= 1) m = fmaxf(m, __shfl_xor(m, d));
    const float sh = acc - m;             // single f32 sub (identical op to ref)
    const float ex = (float)exp((double)sh);
    exs[o] = ex;
    __syncthreads();
    if (o == 0) {
        double sd = 0.0;
        for (int i = 0; i < 64; ++i) sd += (double)exs[i];
        s32s = (float)sd;                 // within ~2 ulp of np's f32 sum -> harmless
    }
    __syncthreads();
    const float log_s = (float)log((double)s32s);
    const float lp = sh - log_s;          // f32
    const float pr = (float)exp((double)lp);

    // first-index argmax over f32 lp (np.argmax semantics)
    float av = lp; int ai = o;
    #pragma unroll
    for (int d = 1; d < 64; d <<= 1) {
        const float ov = __shfl_xor(av, d);
        const int oi = __shfl_xor(ai, d);
        if (ov > av || (ov == av && oi < ai)) { av = ov; ai = oi; }
    }

    out[BSZ + (size_t)b * OUTC + o] = lp;              // logprobs
    out[BSZ + 16384 + (size_t)b * OUTC + o] = pr;      // probs
    if (o == 0) out[b] = (float)ai;                    // preds
}

// ---------------- host ----------------
extern "C" void kernel_launch(void* const* d_in, const int* in_sizes, int n_in,
                              void* d_out, int out_size, void* d_ws, size_t ws_size,
                              hipStream_t stream) {
    const int*   x     = (const int*)d_in[0];
    const float* emb   = (const float*)d_in[1];
    const float* Wi2h  = (const float*)d_in[2];
    const float* b_ih  = (const float*)d_in[3];
    const float* Wi2o  = (const float*)d_in[4];
    const float* b_io  = (const float*)d_in[5];
    const float* Wo2o  = (const float*)d_in[6];
    const float* b_oo  = (const float*)d_in[7];
    const float* Wpred = (const float*)d_in[8];
    const float* b_p   = (const float*)d_in[9];
    float* ws  = (float*)d_ws;
    float* out = (float*)d_out;

    detect_x<<<1, 256, 0, stream>>>(x, ws);
    scan_all<<<dim3(64), 512, 0, stream>>>(x, emb, Wi2h, b_ih, Wi2o, b_io,
                                           Wo2o, b_oo, ws);
    final_k<<<dim3(256), 64, 0, stream>>>(Wpred, b_p, ws, out);
}

// Round 8
// 29484.991 us; speedup vs baseline: 2.9733x; 2.9733x over previous
//
#include <hip/hip_runtime.h>

#define T_STEPS 1024
#define BSZ 256
#define HD 256
#define OUTC 64

// ---------------- ws layout (float offsets) ----------------
static const size_t OFF_SUM  = 0;        // [256][256] f32  (Sum_t outs)
static const size_t OFF_FLAG = 65536;    // int flag (x is int64?)
static const size_t OFF_WT   = 65792;    // 3 x [512][256] f32 transposed weights
// total ~460K floats ~= 1.8MB

// x-dtype detector: if x is int64, all sampled high 32-bit words are zero.
__global__ void detect_x(const int* __restrict__ x, float* __restrict__ ws) {
    __shared__ int nonzero;
    if (threadIdx.x == 0) nonzero = 0;
    __syncthreads();
    if (x[2 * threadIdx.x + 1] != 0) nonzero = 1;   // benign same-value race
    __syncthreads();
    if (threadIdx.x == 0) *(int*)(ws + OFF_FLAG) = (nonzero == 0) ? 1 : 0;
}

// Transposed weight views: WT[z][k][j] = W_z[j][k]  (values identical, so the
// FMA chains below are bit-identical to R7's row-major reads).
__global__ void prep_transpose(const float* __restrict__ Wi2h,
                               const float* __restrict__ Wi2o,
                               const float* __restrict__ Wo2o,
                               float* __restrict__ ws) {
    const int k = blockIdx.x;            // 0..511
    const int z = blockIdx.y;            // 0..2
    const int j = threadIdx.x;           // 0..255
    const float* src = (z == 0) ? Wi2h : (z == 1) ? Wi2o : Wo2o;
    ws[OFF_WT + (size_t)z * 131072 + (size_t)k * 256 + j] = src[(size_t)j * 512 + k];
}

// Bit-faithful f32 scan, coalesced-weight version. Each block owns 4 batch
// rows for all 1024 steps; thread (s,j) handles rows 2s,2s+1 at column j.
// Chains: k-ascending sequential fmaf, e-part then h-part (identical order
// and values to the validated R7 kernel — only the memory layout changed).
__global__ __launch_bounds__(512) void scan_all(
    const int* __restrict__ x, const float* __restrict__ emb,
    const float* __restrict__ bih, const float* __restrict__ bio,
    const float* __restrict__ boo, float* __restrict__ ws) {
    const int tid = threadIdx.x;
    const int j = tid & 255;          // output column
    const int s = tid >> 8;           // slot 0..1 -> rows bl = 2s, 2s+1
    const int bl0 = s * 2, bl1 = s * 2 + 1;
    const int b0 = blockIdx.x * 4;
    const int mode64 = *(const int*)(ws + OFF_FLAG);

    const float* __restrict__ WhT  = ws + OFF_WT;            // [512][256]
    const float* __restrict__ WioT = WhT + 131072;           // [512][256]
    const float* __restrict__ WooT = WhT + 262144;           // [512][256]
    const float* __restrict__ WhTj  = WhT + j;
    const float* __restrict__ WioTj = WioT + j;
    const float* __restrict__ WooTj = WooT + j;

    __shared__ __align__(16) float eL[4][256];
    __shared__ __align__(16) float hPing[4][256];
    __shared__ __align__(16) float hPong[4][256];
    __shared__ __align__(16) float oL[4][256];
    __shared__ float sumL[4][256];
    __shared__ int tokL[4];

    hPing[bl0][j] = 0.f; hPing[bl1][j] = 0.f;   // h_0 = 0
    sumL[bl0][j] = 0.f;  sumL[bl1][j] = 0.f;
    __syncthreads();

    const float bih_j = bih[j], bio_j = bio[j], boo_j = boo[j];

    for (int t = 0; t < T_STEPS; ++t) {
        if (tid < 4) {
            const int idx = t * BSZ + b0 + tid;
            tokL[tid] = mode64 ? x[2 * idx] : x[idx];
        }
        __syncthreads();
        eL[bl0][j] = emb[(size_t)tokL[bl0] * HD + j];
        eL[bl1][j] = emb[(size_t)tokL[bl1] * HD + j];
        __syncthreads();

        const float (*hO)[256] = (t & 1) ? hPong : hPing;
        float (*hN)[256]       = (t & 1) ? hPing : hPong;
        const float4* __restrict__ e0p = (const float4*)eL[bl0];
        const float4* __restrict__ e1p = (const float4*)eL[bl1];
        const float4* __restrict__ h0p = (const float4*)hO[bl0];
        const float4* __restrict__ h1p = (const float4*)hO[bl1];

        // ---- h_new[j], o[j]: FMA chain over k = 0..511 (e part then h part)
        float ah0 = 0.f, ah1 = 0.f, ao0 = 0.f, ao1 = 0.f;
        #pragma unroll 4
        for (int q = 0; q < 64; ++q) {              // k = 0..255 : e part
            const float4 e0 = e0p[q], e1 = e1p[q];
            const float* e0a = (const float*)&e0;
            const float* e1a = (const float*)&e1;
            #pragma unroll
            for (int c = 0; c < 4; ++c) {
                const float wh = WhTj[(size_t)(q * 4 + c) * 256];
                const float wo = WioTj[(size_t)(q * 4 + c) * 256];
                ah0 = fmaf(e0a[c], wh, ah0); ah1 = fmaf(e1a[c], wh, ah1);
                ao0 = fmaf(e0a[c], wo, ao0); ao1 = fmaf(e1a[c], wo, ao1);
            }
        }
        #pragma unroll 4
        for (int q = 0; q < 64; ++q) {              // k = 256..511 : h part
            const float4 h0 = h0p[q], h1 = h1p[q];
            const float* h0a = (const float*)&h0;
            const float* h1a = (const float*)&h1;
            #pragma unroll
            for (int c = 0; c < 4; ++c) {
                const float wh = WhTj[(size_t)(256 + q * 4 + c) * 256];
                const float wo = WioTj[(size_t)(256 + q * 4 + c) * 256];
                ah0 = fmaf(h0a[c], wh, ah0); ah1 = fmaf(h1a[c], wh, ah1);
                ao0 = fmaf(h0a[c], wo, ao0); ao1 = fmaf(h1a[c], wo, ao1);
            }
        }
        const float hn0 = ah0 + bih_j, hn1 = ah1 + bih_j;  // + b_i2h
        const float on0 = ao0 + bio_j, on1 = ao1 + bio_j;  // + b_i2o
        hN[bl0][j] = hn0; hN[bl1][j] = hn1;
        oL[bl0][j] = on0; oL[bl1][j] = on1;
        __syncthreads();

        // ---- out[j]: FMA chain over k = 0..511 (h_new part then o part)
        const float4* __restrict__ n0p = (const float4*)hN[bl0];
        const float4* __restrict__ n1p = (const float4*)hN[bl1];
        const float4* __restrict__ o0p = (const float4*)oL[bl0];
        const float4* __restrict__ o1p = (const float4*)oL[bl1];
        float ac0 = 0.f, ac1 = 0.f;
        #pragma unroll 4
        for (int q = 0; q < 64; ++q) {              // h_new part
            const float4 v0 = n0p[q], v1 = n1p[q];
            const float* v0a = (const float*)&v0;
            const float* v1a = (const float*)&v1;
            #pragma unroll
            for (int c = 0; c < 4; ++c) {
                const float w = WooTj[(size_t)(q * 4 + c) * 256];
                ac0 = fmaf(v0a[c], w, ac0);
                ac1 = fmaf(v1a[c], w, ac1);
            }
        }
        #pragma unroll 4
        for (int q = 0; q < 64; ++q) {              // o part
            const float4 v0 = o0p[q], v1 = o1p[q];
            const float* v0a = (const float*)&v0;
            const float* v1a = (const float*)&v1;
            #pragma unroll
            for (int c = 0; c < 4; ++c) {
                const float w = WooTj[(size_t)(256 + q * 4 + c) * 256];
                ac0 = fmaf(v0a[c], w, ac0);
                ac1 = fmaf(v1a[c], w, ac1);
            }
        }
        // Sum_t accumulation, t-ascending, f32 (np.mean axis-0 order)
        sumL[bl0][j] += (ac0 + boo_j);
        sumL[bl1][j] += (ac1 + boo_j);
        __syncthreads();
    }

    ws[OFF_SUM + (size_t)(b0 + bl0) * 256 + j] = sumL[bl0][j];
    ws[OFF_SUM + (size_t)(b0 + bl1) * 256 + j] = sumL[bl1][j];
}

// encoded = Sum/1024 (exact); logits = seq-k FMA + b_pred; log_softmax with
// f64-CR exp/log; first-index argmax over f32 lp.
__global__ __launch_bounds__(64) void final_k(
    const float* __restrict__ Wpred, const float* __restrict__ bpred,
    const float* __restrict__ ws, float* __restrict__ out) {
    const int b = blockIdx.x, o = threadIdx.x;
    __shared__ float enc[256];
    __shared__ float exs[64];
    __shared__ float s32s;

    #pragma unroll
    for (int u = 0; u < 4; ++u)
        enc[o * 4 + u] = ws[OFF_SUM + (size_t)b * 256 + o * 4 + u] * (1.0f / 1024.0f);
    __syncthreads();

    float acc = 0.f;
    for (int e = 0; e < 256; ++e)
        acc = fmaf(enc[e], Wpred[(size_t)o * 256 + e], acc);
    acc += bpred[o];                      // logits[b][o], f32

    float m = acc;
    #pragma unroll
    for (int d = 1; d < 64; d <<= 1) m = fmaxf(m, __shfl_xor(m, d));
    const float sh = acc - m;
    const float ex = (float)exp((double)sh);
    exs[o] = ex;
    __syncthreads();
    if (o == 0) {
        double sd = 0.0;
        for (int i = 0; i < 64; ++i) sd += (double)exs[i];
        s32s = (float)sd;
    }
    __syncthreads();
    const float log_s = (float)log((double)s32s);
    const float lp = sh - log_s;
    const float pr = (float)exp((double)lp);

    float av = lp; int ai = o;
    #pragma unroll
    for (int d = 1; d < 64; d <<= 1) {
        const float ov = __shfl_xor(av, d);
        const int oi = __shfl_xor(ai, d);
        if (ov > av || (ov == av && oi < ai)) { av = ov; ai = oi; }
    }

    out[BSZ + (size_t)b * OUTC + o] = lp;              // logprobs
    out[BSZ + 16384 + (size_t)b * OUTC + o] = pr;      // probs
    if (o == 0) out[b] = (float)ai;                    // preds
}

// ---------------- host ----------------
extern "C" void kernel_launch(void* const* d_in, const int* in_sizes, int n_in,
                              void* d_out, int out_size, void* d_ws, size_t ws_size,
                              hipStream_t stream) {
    const int*   x     = (const int*)d_in[0];
    const float* emb   = (const float*)d_in[1];
    const float* Wi2h  = (const float*)d_in[2];
    const float* b_ih  = (const float*)d_in[3];
    const float* Wi2o  = (const float*)d_in[4];
    const float* b_io  = (const float*)d_in[5];
    const float* Wo2o  = (const float*)d_in[6];
    const float* b_oo  = (const float*)d_in[7];
    const float* Wpred = (const float*)d_in[8];
    const float* b_p   = (const float*)d_in[9];
    float* ws  = (float*)d_ws;
    float* out = (float*)d_out;

    detect_x<<<1, 256, 0, stream>>>(x, ws);
    prep_transpose<<<dim3(512, 3), 256, 0, stream>>>(Wi2h, Wi2o, Wo2o, ws);
    scan_all<<<dim3(64), 512, 0, stream>>>(x, emb, b_ih, b_io, b_oo, ws);
    final_k<<<dim3(256), 64, 0, stream>>>(Wpred, b_p, ws, out);
}